// Round 4
// baseline (944.316 us; speedup 1.0000x reference)
//
#include <hip/hip_runtime.h>
#include <hip/hip_cooperative_groups.h>

namespace cg = cooperative_groups;

#define N_NODES 16384
#define N_EDGES 8192
#define MAXD 32
#define NODE_CAP 64
#define GRID_C 1024
#define BLK 256

struct Ctx {
    const float *v, *Wv, *ef, *We, *H, *be, *Wo;
    int *edge_cnt, *node_cnt, *ticket, *edge_nodes, *node_edges;
    float *pe, *eexp, *s_arr, *vsrc, *msg, *msgo;
};

// ---------------- 32-row GEMM tile: C[blk*32 ..][128] = A[.,128] @ B[128,128] ----------------
// lds: 32*128 (Bs) + 32*32 (As) floats = 20 KB
__device__ __forceinline__ void gemm128_body(float* lds, const float* __restrict__ A,
    const float* __restrict__ B, float* __restrict__ C, int blk)
{
    float (*Bs)[128] = (float(*)[128])lds;
    float (*As)[32]  = (float(*)[32])(lds + 32 * 128);
    const int tid  = threadIdx.x;
    const int row0 = blk * 32;
    const int r    = tid >> 4;
    const int c0   = (tid & 15) * 8;

    float acc[2][8];
#pragma unroll
    for (int i = 0; i < 2; ++i)
#pragma unroll
        for (int j = 0; j < 8; ++j) acc[i][j] = 0.f;

    for (int kt = 0; kt < 128; kt += 32) {
#pragma unroll
        for (int u0 = 0; u0 < 4; ++u0) {                 // Bs: 32x128 = 1024 float4
            int u = u0 * 256 + tid;
            int kk = u >> 5, cc = (u & 31) * 4;
            *(float4*)&Bs[kk][cc] = *(const float4*)&B[(kt + kk) * 128 + cc];
        }
        {                                                 // As: 32x32 = 256 float4
            int rr = tid >> 3, cc = (tid & 7) * 4;
            *(float4*)&As[rr][cc] = *(const float4*)&A[(row0 + rr) * 128 + kt + cc];
        }
        __syncthreads();
#pragma unroll
        for (int k = 0; k < 32; ++k) {
            float a0 = As[r][k];
            float a1 = As[r + 16][k];
#pragma unroll
            for (int j = 0; j < 8; ++j) {
                float b = Bs[k][c0 + j];
                acc[0][j] = fmaf(a0, b, acc[0][j]);
                acc[1][j] = fmaf(a1, b, acc[1][j]);
            }
        }
        __syncthreads();
    }
#pragma unroll
    for (int i = 0; i < 2; ++i) {
        int row = row0 + r + i * 16;
#pragma unroll
        for (int j = 0; j < 8; ++j) C[row * 128 + c0 + j] = acc[i][j];
    }
}

// ---------------- pe[n,h] = ef[n,:] @ We[:,h] ----------------
__device__ __forceinline__ void ph_pe(const Ctx& c, int g)
{
    if (g >= N_NODES * 8) return;
    int n = g >> 3, h = g & 7;
    const float4* ef4 = (const float4*)c.ef + n * 16;
    float p = 0.f;
#pragma unroll
    for (int d4 = 0; d4 < 16; ++d4) {
        float4 x = ef4[d4];
        p += x.x * c.We[(d4 * 4 + 0) * 8 + h] + x.y * c.We[(d4 * 4 + 1) * 8 + h]
           + x.z * c.We[(d4 * 4 + 2) * 8 + h] + x.w * c.We[(d4 * 4 + 3) * 8 + h];
    }
    c.pe[g] = p;
}

// ---------------- H scan: one ticket = one node row (8192 floats = 2048 float4) ----------------
// builds edge member lists (edge_nodes[e][<=32]) AND padded node adjacency
// (node_edges[n][<=64]) in a single pass. 8 batched loads/thread -> BW-robust.
__device__ __forceinline__ void scan_rows(const Ctx& c, int* srow)
{
    const int tid = threadIdx.x;
    const float4* H4 = (const float4*)c.H;
    for (;;) {
        __syncthreads();
        if (tid == 0) *srow = atomicAdd(c.ticket, 1);
        __syncthreads();
        const int row = *srow;
        if (row >= N_NODES) break;
        const float4* Hr = H4 + (size_t)row * (N_EDGES / 4);
        float4 x[8];
#pragma unroll
        for (int rb = 0; rb < 8; ++rb) x[rb] = Hr[rb * 256 + tid];
        int cloc = 0;
#pragma unroll
        for (int rb = 0; rb < 8; ++rb) {
            const float* xs = (const float*)&x[rb];
            if (xs[0] != 0.f || xs[1] != 0.f || xs[2] != 0.f || xs[3] != 0.f) {
#pragma unroll
                for (int k2 = 0; k2 < 4; ++k2) {
                    if (xs[k2] != 0.f) {
                        int e = (rb * 256 + tid) * 4 + k2;
                        int p = atomicAdd(&c.edge_cnt[e], 1);
                        if (p < MAXD) c.edge_nodes[e * MAXD + p] = row;
                        ++cloc;
                    }
                }
            }
        }
        if (cloc) {
            int np = atomicAdd(&c.node_cnt[row], cloc);
#pragma unroll
            for (int rb = 0; rb < 8; ++rb) {
                const float* xs = (const float*)&x[rb];
#pragma unroll
                for (int k2 = 0; k2 < 4; ++k2) {
                    if (xs[k2] != 0.f) {
                        if (np < NODE_CAP)
                            c.node_edges[row * NODE_CAP + np] = (rb * 256 + tid) * 4 + k2;
                        ++np;
                    }
                }
            }
        }
    }
}

// ---------------- eexp[e,h] = exp(be[h] + sum_j pe[n_j,h]) ----------------
__device__ __forceinline__ void ph_eexp(const Ctx& c, int g)
{
    if (g >= N_EDGES * 8) return;
    int e = g >> 3, h = g & 7;
    int cnt = min(c.edge_cnt[e], MAXD);
    float s = c.be[h];
    for (int j = 0; j < cnt; ++j) s += c.pe[c.edge_nodes[e * MAXD + j] * 8 + h];
    c.eexp[g] = __expf(s);      // softmax shift-invariant; |s| ~ O(1) -> safe
}

// ---------------- s_arr[n,h] = 1/(sum_{e in n} eexp[e,h] + eps) ----------------
__device__ __forceinline__ void ph_z(const Ctx& c, int g)
{
    if (g >= N_NODES * 8) return;
    int n = g >> 3, h = g & 7;
    int cnt = min(c.node_cnt[n], NODE_CAP);
    float z = 0.f;
    for (int i = 0; i < cnt; ++i) z += c.eexp[c.node_edges[n * NODE_CAP + i] * 8 + h];
    c.s_arr[g] = 1.0f / (z + 1e-10f);
}

// ---------------- msg[e,c] = eexp[e,h]*sum_j s[n_j,h]*vsrc[n_j,c] (float4 lanes) ----------------
__device__ __forceinline__ void ph_msg(const Ctx& c, int g)
{
    int e = g >> 5, c4 = g & 31, h = c4 >> 2;
    int cnt = min(c.edge_cnt[e], MAXD);
    float eh = c.eexp[e * 8 + h];
    const float4* v4 = (const float4*)c.vsrc;
    float4 acc = {0.f, 0.f, 0.f, 0.f};
    for (int j = 0; j < cnt; ++j) {
        int n = c.edge_nodes[e * MAXD + j];
        float t = c.s_arr[n * 8 + h];
        float4 x = v4[n * 32 + c4];
        acc.x = fmaf(t, x.x, acc.x); acc.y = fmaf(t, x.y, acc.y);
        acc.z = fmaf(t, x.z, acc.z); acc.w = fmaf(t, x.w, acc.w);
    }
    acc.x *= eh; acc.y *= eh; acc.z *= eh; acc.w *= eh;
    ((float4*)c.msg)[g] = acc;
}

// ---------------- cooperative mega-kernel ----------------
__global__ __launch_bounds__(BLK, 4) void coop_k(Ctx c)
{
    __shared__ float smem[32 * 128 + 32 * 32 + 4];
    int* srow = (int*)&smem[32 * 128 + 32 * 32];
    cg::grid_group grid = cg::this_grid();
    const int b = blockIdx.x, tid = threadIdx.x;
    const int g = b * BLK + tid;

    // P0: zero counters + ticket
    if (g < N_EDGES) c.edge_cnt[g] = 0;
    {
        int g2 = g - N_EDGES;
        if (g2 >= 0 && g2 < N_NODES) c.node_cnt[g2] = 0;
    }
    if (g == 0) *c.ticket = 0;
    grid.sync();

    // P1: vsrc GEMM (blocks 0..511) ∥ pe (blocks 512..1023), then all join the H scan
    if (b < 512) gemm128_body(smem, c.v, c.Wv, c.vsrc, b);
    else         ph_pe(c, (b - 512) * BLK + tid);
    scan_rows(c, srow);
    grid.sync();

    ph_eexp(c, g);
    grid.sync();

    ph_z(c, g);
    grid.sync();

    ph_msg(c, g);
    grid.sync();

    // P5: msgo = msg @ Wo (Wo commutes with aggregation: rst@Wo = H@(msg@Wo))
    if (b < N_EDGES / 32) gemm128_body(smem, c.msg, c.Wo, c.msgo, b);
}

// ---------------- fallback path (if cooperative launch is refused at capture) ----------------
__global__ __launch_bounds__(BLK, 4) void p1_k(Ctx c)
{
    __shared__ float smem[32 * 128 + 32 * 32 + 4];
    int* srow = (int*)&smem[32 * 128 + 32 * 32];
    const int b = blockIdx.x;
    if (b < 512) gemm128_body(smem, c.v, c.Wv, c.vsrc, b);
    else         ph_pe(c, (b - 512) * BLK + threadIdx.x);
    scan_rows(c, srow);
}
__global__ __launch_bounds__(BLK) void eexp_k(Ctx c) { ph_eexp(c, blockIdx.x * BLK + threadIdx.x); }
__global__ __launch_bounds__(BLK) void zf_k(Ctx c)   { ph_z(c, blockIdx.x * BLK + threadIdx.x); }
__global__ __launch_bounds__(BLK) void msgf_k(Ctx c) { ph_msg(c, blockIdx.x * BLK + threadIdx.x); }
__global__ __launch_bounds__(BLK, 4) void gemmWo_k(Ctx c)
{
    __shared__ float smem[32 * 128 + 32 * 32];
    gemm128_body(smem, c.msg, c.Wo, c.msgo, blockIdx.x);
}

// ---------------- final fused: h = q + sum msgo ; out = h + relu(h@W1+b1)@W2 + b2 ----------------
__global__ __launch_bounds__(256) void ffn_agg_k(const float* __restrict__ q,
    const int* __restrict__ node_cnt, const int* __restrict__ node_edges,
    const float* __restrict__ msgo, const float* __restrict__ W1,
    const float* __restrict__ b1, const float* __restrict__ W2,
    const float* __restrict__ b2, float* __restrict__ out)
{
    __shared__ float Hs[32][128];                     // 16 KB, persistent
    __shared__ char dyn[65536];                       // 64 KB overlay
    float (*B1s)[256] = (float(*)[256])dyn;
    float (*Ts)[256]  = (float(*)[256])dyn;
    float (*B2s)[128] = (float(*)[128])(dyn + 32768);

    const int tid  = threadIdx.x;
    const int row0 = blockIdx.x * 32;

    {   // aggregate h rows into Hs
        int r = tid >> 3, lc = tid & 7;
        int n = row0 + r;
        const float4* q4 = (const float4*)q;
        const float4* m4 = (const float4*)msgo;
        float4 acc[4];
#pragma unroll
        for (int u = 0; u < 4; ++u) acc[u] = q4[n * 32 + lc + 8 * u];
        int cnt = min(node_cnt[n], NODE_CAP);
        for (int i = 0; i < cnt; ++i) {
            int e = node_edges[n * NODE_CAP + i];
#pragma unroll
            for (int u = 0; u < 4; ++u) {
                float4 x = m4[e * 32 + lc + 8 * u];
                acc[u].x += x.x; acc[u].y += x.y; acc[u].z += x.z; acc[u].w += x.w;
            }
        }
#pragma unroll
        for (int u = 0; u < 4; ++u)
            *(float4*)&Hs[r][(lc + 8 * u) * 4] = acc[u];
    }
    __syncthreads();

    const int r  = tid >> 4;
    const int cb = tid & 15;

    // phase A: T = relu(h @ W1 + b1)
    float acc[2][16];
#pragma unroll
    for (int i = 0; i < 2; ++i)
#pragma unroll
        for (int j = 0; j < 16; ++j) acc[i][j] = 0.f;

    for (int kt = 0; kt < 128; kt += 64) {
        for (int u = tid; u < 4096; u += 256) {
            int kk = u >> 6, cc = (u & 63) * 4;
            *(float4*)&B1s[kk][cc] = *(const float4*)&W1[(kt + kk) * 256 + cc];
        }
        __syncthreads();
#pragma unroll
        for (int k = 0; k < 64; ++k) {
            float a0 = Hs[r][kt + k], a1 = Hs[r + 16][kt + k];
#pragma unroll
            for (int j = 0; j < 16; ++j) {
                float b = B1s[k][cb * 16 + j];
                acc[0][j] = fmaf(a0, b, acc[0][j]);
                acc[1][j] = fmaf(a1, b, acc[1][j]);
            }
        }
        __syncthreads();
    }
#pragma unroll
    for (int i = 0; i < 2; ++i)
#pragma unroll
        for (int j = 0; j < 16; ++j) {
            int col = cb * 16 + j;
            Ts[r + i * 16][col] = fmaxf(acc[i][j] + b1[col], 0.f);
        }

    // phase B: out = h + T @ W2 + b2
    float acc2[2][8];
#pragma unroll
    for (int i = 0; i < 2; ++i)
#pragma unroll
        for (int j = 0; j < 8; ++j) acc2[i][j] = 0.f;

    for (int kt = 0; kt < 256; kt += 64) {
        for (int u = tid; u < 2048; u += 256) {
            int kk = u >> 5, cc = (u & 31) * 4;
            *(float4*)&B2s[kk][cc] = *(const float4*)&W2[(kt + kk) * 128 + cc];
        }
        __syncthreads();                              // first one also publishes Ts
#pragma unroll
        for (int k = 0; k < 64; ++k) {
            float a0 = Ts[r][kt + k], a1 = Ts[r + 16][kt + k];
#pragma unroll
            for (int j = 0; j < 8; ++j) {
                float b = B2s[k][cb * 8 + j];
                acc2[0][j] = fmaf(a0, b, acc2[0][j]);
                acc2[1][j] = fmaf(a1, b, acc2[1][j]);
            }
        }
        __syncthreads();
    }
#pragma unroll
    for (int i = 0; i < 2; ++i) {
        int row = row0 + r + i * 16;
#pragma unroll
        for (int j = 0; j < 8; ++j) {
            int col = cb * 8 + j;
            out[row * 128 + col] = Hs[r + i * 16][col] + acc2[i][j] + b2[col];
        }
    }
}

extern "C" void kernel_launch(void* const* d_in, const int* in_sizes, int n_in,
                              void* d_out, int out_size, void* d_ws, size_t ws_size,
                              hipStream_t stream)
{
    const float* q  = (const float*)d_in[0];
    // d_in[1] = k : dead (per-node q·k dot is segment-constant, cancels in softmax)
    const float* v  = (const float*)d_in[2];
    const float* ef = (const float*)d_in[3];
    const float* H  = (const float*)d_in[4];
    // d_in[5] = Wq, d_in[6] = Wk : dead
    const float* Wv = (const float*)d_in[7];
    const float* We = (const float*)d_in[8];
    const float* be = (const float*)d_in[9];
    const float* Wo = (const float*)d_in[10];
    const float* W1 = (const float*)d_in[11];
    const float* b1 = (const float*)d_in[12];
    const float* W2 = (const float*)d_in[13];
    const float* b2 = (const float*)d_in[14];
    float* out = (float*)d_out;

    char* w = (char*)d_ws;
    auto carve = [&](size_t bytes) -> void* {
        void* p = (void*)w;
        w += (bytes + 255) & ~(size_t)255;
        return p;
    };
    int* edge_cnt   = (int*)carve(N_EDGES * 4);
    int* node_cnt   = (int*)carve(N_NODES * 4);
    int* ticket     = (int*)carve(256);
    size_t zero_bytes = (size_t)(w - (char*)d_ws);
    int* edge_nodes = (int*)carve((size_t)N_EDGES * MAXD * 4);
    int* node_edges = (int*)carve((size_t)N_NODES * NODE_CAP * 4);
    float* pe       = (float*)carve((size_t)N_NODES * 8 * 4);
    float* eexp     = (float*)carve((size_t)N_EDGES * 8 * 4);
    float* s_arr    = (float*)carve((size_t)N_NODES * 8 * 4);
    float* vsrc     = (float*)carve((size_t)N_NODES * 128 * 4);
    float* msg      = (float*)carve((size_t)N_EDGES * 128 * 4);
    float* msgo     = (float*)carve((size_t)N_EDGES * 128 * 4);
    (void)ws_size; (void)in_sizes; (void)n_in; (void)out_size;

    Ctx ctx;
    ctx.v = v; ctx.Wv = Wv; ctx.ef = ef; ctx.We = We; ctx.H = H; ctx.be = be; ctx.Wo = Wo;
    ctx.edge_cnt = edge_cnt; ctx.node_cnt = node_cnt; ctx.ticket = ticket;
    ctx.edge_nodes = edge_nodes; ctx.node_edges = node_edges;
    ctx.pe = pe; ctx.eexp = eexp; ctx.s_arr = s_arr;
    ctx.vsrc = vsrc; ctx.msg = msg; ctx.msgo = msgo;

    void* args[] = { &ctx };
    hipError_t st = hipLaunchCooperativeKernel((const void*)coop_k,
                                               dim3(GRID_C), dim3(BLK), args, 0, stream);
    if (st != hipSuccess) {
        // fallback: same phases as separate dispatches
        hipMemsetAsync(d_ws, 0, zero_bytes, stream);
        p1_k<<<GRID_C, BLK, 0, stream>>>(ctx);
        eexp_k<<<(N_EDGES * 8) / BLK, BLK, 0, stream>>>(ctx);
        zf_k<<<(N_NODES * 8) / BLK, BLK, 0, stream>>>(ctx);
        msgf_k<<<(N_EDGES * 32) / BLK, BLK, 0, stream>>>(ctx);
        gemmWo_k<<<N_EDGES / 32, BLK, 0, stream>>>(ctx);
    }
    ffn_agg_k<<<N_NODES / 32, 256, 0, stream>>>(q, node_cnt, node_edges, msgo,
                                                W1, b1, W2, b2, out);
}

// Round 5
// 312.438 us; speedup vs baseline: 3.0224x; 3.0224x over previous
//
#include <hip/hip_runtime.h>

#define N_NODES 16384
#define N_EDGES 8192
#define MAXD 32
#define NODE_CAP 64

// ---- scan helper: process one float4 of H at flat float4-index i ----
__device__ __forceinline__ void scan_f4(int* __restrict__ edge_cnt,
    int* __restrict__ edge_nodes, int* __restrict__ node_cnt,
    int* __restrict__ node_edges, float4 x, unsigned i)
{
    int m = (x.x != 0.f ? 1 : 0) | (x.y != 0.f ? 2 : 0)
          | (x.z != 0.f ? 4 : 0) | (x.w != 0.f ? 8 : 0);
    if (!m) return;
    unsigned base = i * 4u;
    int n  = (int)(base >> 13);          // 8192 floats per row
    int e0 = (int)(base & 8191u);
    int np = atomicAdd(&node_cnt[n], __popc(m));
    if (m & 1) { int p = atomicAdd(&edge_cnt[e0+0], 1); if (p < MAXD) edge_nodes[(e0+0)*MAXD+p] = n;
                 if (np < NODE_CAP) node_edges[n*NODE_CAP+np] = e0+0; ++np; }
    if (m & 2) { int p = atomicAdd(&edge_cnt[e0+1], 1); if (p < MAXD) edge_nodes[(e0+1)*MAXD+p] = n;
                 if (np < NODE_CAP) node_edges[n*NODE_CAP+np] = e0+1; ++np; }
    if (m & 4) { int p = atomicAdd(&edge_cnt[e0+2], 1); if (p < MAXD) edge_nodes[(e0+2)*MAXD+p] = n;
                 if (np < NODE_CAP) node_edges[n*NODE_CAP+np] = e0+2; ++np; }
    if (m & 8) { int p = atomicAdd(&edge_cnt[e0+3], 1); if (p < MAXD) edge_nodes[(e0+3)*MAXD+p] = n;
                 if (np < NODE_CAP) node_edges[n*NODE_CAP+np] = e0+3; ++np; }
}

// ---------------- phase 1: vsrc GEMM (no LDS) ∥ pe projection ∥ H scan ----------------
// blocks [0,512): vsrc = v @ Wv ; [512,1024): pe[n,h] ; [1024,5120): H scan + both adjacency lists
__global__ __launch_bounds__(256) void phase1_k(
    const float* __restrict__ v, const float* __restrict__ Wv,
    const float* __restrict__ ef, const float* __restrict__ We,
    const float* __restrict__ H,
    int* __restrict__ edge_cnt, int* __restrict__ edge_nodes,
    int* __restrict__ node_cnt, int* __restrict__ node_edges,
    float* __restrict__ vsrc, float* __restrict__ pe)
{
    const int b = blockIdx.x, tid = threadIdx.x;
    if (b < 512) {
        // 32 rows per block; B (64 KB) streams through L1/L2 (wave-broadcast)
        const int row0 = b * 32;
        const int r  = tid >> 4;          // 0..15 -> rows r, r+16
        const int c0 = (tid & 15) * 8;    // 8 output cols
        const float4* A4 = (const float4*)v;
        const float4* B4 = (const float4*)Wv;
        float acc[2][8];
#pragma unroll
        for (int i = 0; i < 2; ++i)
#pragma unroll
            for (int j = 0; j < 8; ++j) acc[i][j] = 0.f;
#pragma unroll 4
        for (int k4 = 0; k4 < 32; ++k4) {
            float4 a0 = A4[(size_t)(row0 + r) * 32 + k4];
            float4 a1 = A4[(size_t)(row0 + r + 16) * 32 + k4];
#pragma unroll
            for (int kk = 0; kk < 4; ++kk) {
                int k = k4 * 4 + kk;
                float4 b0 = B4[k * 32 + (c0 >> 2)];
                float4 b1 = B4[k * 32 + (c0 >> 2) + 1];
                float av0 = kk == 0 ? a0.x : kk == 1 ? a0.y : kk == 2 ? a0.z : a0.w;
                float av1 = kk == 0 ? a1.x : kk == 1 ? a1.y : kk == 2 ? a1.z : a1.w;
                acc[0][0] = fmaf(av0, b0.x, acc[0][0]); acc[0][1] = fmaf(av0, b0.y, acc[0][1]);
                acc[0][2] = fmaf(av0, b0.z, acc[0][2]); acc[0][3] = fmaf(av0, b0.w, acc[0][3]);
                acc[0][4] = fmaf(av0, b1.x, acc[0][4]); acc[0][5] = fmaf(av0, b1.y, acc[0][5]);
                acc[0][6] = fmaf(av0, b1.z, acc[0][6]); acc[0][7] = fmaf(av0, b1.w, acc[0][7]);
                acc[1][0] = fmaf(av1, b0.x, acc[1][0]); acc[1][1] = fmaf(av1, b0.y, acc[1][1]);
                acc[1][2] = fmaf(av1, b0.z, acc[1][2]); acc[1][3] = fmaf(av1, b0.w, acc[1][3]);
                acc[1][4] = fmaf(av1, b1.x, acc[1][4]); acc[1][5] = fmaf(av1, b1.y, acc[1][5]);
                acc[1][6] = fmaf(av1, b1.z, acc[1][6]); acc[1][7] = fmaf(av1, b1.w, acc[1][7]);
            }
        }
#pragma unroll
        for (int i = 0; i < 2; ++i) {
            int row = row0 + r + i * 16;
            float4 o0 = {acc[i][0], acc[i][1], acc[i][2], acc[i][3]};
            float4 o1 = {acc[i][4], acc[i][5], acc[i][6], acc[i][7]};
            *(float4*)&vsrc[row * 128 + c0]     = o0;
            *(float4*)&vsrc[row * 128 + c0 + 4] = o1;
        }
    } else if (b < 1024) {
        int g = (b - 512) * 256 + tid;   // (n,h)
        int n = g >> 3, h = g & 7;
        const float4* ef4 = (const float4*)ef + n * 16;
        float p = 0.f;
#pragma unroll
        for (int d4 = 0; d4 < 16; ++d4) {
            float4 x = ef4[d4];
            p += x.x * We[(d4 * 4 + 0) * 8 + h] + x.y * We[(d4 * 4 + 1) * 8 + h]
               + x.z * We[(d4 * 4 + 2) * 8 + h] + x.w * We[(d4 * 4 + 3) * 8 + h];
        }
        pe[g] = p;
    } else {
        const float4* H4 = (const float4*)H;
        const unsigned g = (unsigned)(b - 1024) * 256u + tid;   // [0, 2^20)
        const unsigned T = 4096u * 256u;                        // stride
#pragma unroll 1
        for (int it = 0; it < 32; it += 4) {
            float4 x0 = H4[(size_t)(it + 0) * T + g];
            float4 x1 = H4[(size_t)(it + 1) * T + g];
            float4 x2 = H4[(size_t)(it + 2) * T + g];
            float4 x3 = H4[(size_t)(it + 3) * T + g];
            scan_f4(edge_cnt, edge_nodes, node_cnt, node_edges, x0, (unsigned)(it + 0) * T + g);
            scan_f4(edge_cnt, edge_nodes, node_cnt, node_edges, x1, (unsigned)(it + 1) * T + g);
            scan_f4(edge_cnt, edge_nodes, node_cnt, node_edges, x2, (unsigned)(it + 2) * T + g);
            scan_f4(edge_cnt, edge_nodes, node_cnt, node_edges, x3, (unsigned)(it + 3) * T + g);
        }
    }
}

// ---------------- eexp[e,h] = exp(be[h] + sum_j pe[n_j,h]) ----------------
__global__ __launch_bounds__(256) void eexp_k(const int* __restrict__ edge_cnt,
    const int* __restrict__ edge_nodes, const float* __restrict__ pe,
    const float* __restrict__ be, float* __restrict__ eexp)
{
    int g = blockIdx.x * 256 + threadIdx.x;   // (e,h) in [0, 65536)
    int e = g >> 3, h = g & 7;
    int cnt = min(edge_cnt[e], MAXD);
    float s = be[h];
    for (int j = 0; j < cnt; ++j) s += pe[edge_nodes[e * MAXD + j] * 8 + h];
    eexp[g] = __expf(s);      // softmax shift-invariant; |s| = O(1) -> safe without max-sub
}

// ---------------- s_arr[n,h] = 1/(sum_{e in n} eexp[e,h] + eps) ----------------
__global__ __launch_bounds__(256) void z_k(const int* __restrict__ node_cnt,
    const int* __restrict__ node_edges, const float* __restrict__ eexp,
    float* __restrict__ s_arr)
{
    int g = blockIdx.x * 256 + threadIdx.x;   // (n,h) in [0, 131072)
    int n = g >> 3, h = g & 7;
    int cnt = min(node_cnt[n], NODE_CAP);
    float z = 0.f;
    for (int i = 0; i < cnt; ++i) z += eexp[node_edges[n * NODE_CAP + i] * 8 + h];
    s_arr[g] = 1.0f / (z + 1e-10f);
}

// ---------------- msg[e,c] = eexp[e,h] * sum_j s[n_j,h]*vsrc[n_j,c] ----------------
__global__ __launch_bounds__(256) void msg_k(const int* __restrict__ edge_cnt,
    const int* __restrict__ edge_nodes, const float* __restrict__ eexp,
    const float* __restrict__ s_arr, const float* __restrict__ vsrc,
    float* __restrict__ msg)
{
    int g = blockIdx.x * 256 + threadIdx.x;   // [0, 262144)
    int e = g >> 5, c4 = g & 31, h = c4 >> 2;
    int cnt = min(edge_cnt[e], MAXD);
    float eh = eexp[e * 8 + h];
    const float4* v4 = (const float4*)vsrc;
    float4 acc = {0.f, 0.f, 0.f, 0.f};
    for (int j = 0; j < cnt; ++j) {
        int n = edge_nodes[e * MAXD + j];
        float t = s_arr[n * 8 + h];
        float4 x = v4[n * 32 + c4];
        acc.x = fmaf(t, x.x, acc.x); acc.y = fmaf(t, x.y, acc.y);
        acc.z = fmaf(t, x.z, acc.z); acc.w = fmaf(t, x.w, acc.w);
    }
    acc.x *= eh; acc.y *= eh; acc.z *= eh; acc.w *= eh;
    ((float4*)msg)[g] = acc;
}

// ---- final fused: rst = sum msg ; h = rst@Wo + q ; out = h + relu(h@W1+b1)@W2 + b2 ----
__global__ __launch_bounds__(256) void ffn_agg_k(const float* __restrict__ q,
    const int* __restrict__ node_cnt, const int* __restrict__ node_edges,
    const float* __restrict__ msg, const float* __restrict__ Wo,
    const float* __restrict__ W1, const float* __restrict__ b1,
    const float* __restrict__ W2, const float* __restrict__ b2,
    float* __restrict__ out)
{
    __shared__ float Hs[32][128];                     // 16 KB, persistent h rows
    __shared__ char dyn[65536];                       // 64 KB overlay
    float (*Rs)[128]  = (float(*)[128])dyn;           // agg rows      [0,16K)
    float (*Wos)[128] = (float(*)[128])(dyn + 16384); // Wo tile       [16K,32K)
    float (*B1s)[256] = (float(*)[256])dyn;           // phase A       [0,64K)
    float (*Ts)[256]  = (float(*)[256])dyn;           // phase B       [0,32K)
    float (*B2s)[128] = (float(*)[128])(dyn + 32768); // phase B       [32K,64K)

    const int tid  = threadIdx.x;
    const int row0 = blockIdx.x * 32;

    // ---- aggregate msg rows into Rs ----
    {
        int r = tid >> 3, lc = tid & 7;
        int n = row0 + r;
        const float4* m4 = (const float4*)msg;
        float4 acc[4] = {{0,0,0,0},{0,0,0,0},{0,0,0,0},{0,0,0,0}};
        int cnt = min(node_cnt[n], NODE_CAP);
        for (int i = 0; i < cnt; ++i) {
            int e = node_edges[n * NODE_CAP + i];
#pragma unroll
            for (int u = 0; u < 4; ++u) {
                float4 x = m4[e * 32 + lc + 8 * u];
                acc[u].x += x.x; acc[u].y += x.y; acc[u].z += x.z; acc[u].w += x.w;
            }
        }
#pragma unroll
        for (int u = 0; u < 4; ++u)
            *(float4*)&Rs[r][(lc + 8 * u) * 4] = acc[u];
    }
    __syncthreads();

    const int r  = tid >> 4;
    const int cb = tid & 15;
    const int c0 = cb * 8;

    // ---- h = Rs @ Wo + q -> Hs ----
    {
        float acc[2][8];
#pragma unroll
        for (int i = 0; i < 2; ++i)
#pragma unroll
            for (int j = 0; j < 8; ++j) acc[i][j] = 0.f;
        for (int kt = 0; kt < 128; kt += 32) {
#pragma unroll
            for (int u0 = 0; u0 < 4; ++u0) {          // Wos: 32x128 = 1024 float4
                int u = u0 * 256 + tid;
                int kk = u >> 5, cc = (u & 31) * 4;
                *(float4*)&Wos[kk][cc] = *(const float4*)&Wo[(kt + kk) * 128 + cc];
            }
            __syncthreads();
#pragma unroll
            for (int k = 0; k < 32; ++k) {
                float a0 = Rs[r][kt + k], a1 = Rs[r + 16][kt + k];
#pragma unroll
                for (int j = 0; j < 8; ++j) {
                    float b = Wos[k][c0 + j];
                    acc[0][j] = fmaf(a0, b, acc[0][j]);
                    acc[1][j] = fmaf(a1, b, acc[1][j]);
                }
            }
            __syncthreads();
        }
#pragma unroll
        for (int i = 0; i < 2; ++i) {
            int row = row0 + r + i * 16;
#pragma unroll
            for (int j = 0; j < 8; ++j)
                Hs[r + i * 16][c0 + j] = acc[i][j] + q[row * 128 + c0 + j];
        }
    }
    __syncthreads();

    // ---- phase A: T = relu(h @ W1 + b1) ----
    float acc[2][16];
#pragma unroll
    for (int i = 0; i < 2; ++i)
#pragma unroll
        for (int j = 0; j < 16; ++j) acc[i][j] = 0.f;

    for (int kt = 0; kt < 128; kt += 64) {
        for (int u = tid; u < 4096; u += 256) {       // B1s 64x256
            int kk = u >> 6, cc = (u & 63) * 4;
            *(float4*)&B1s[kk][cc] = *(const float4*)&W1[(kt + kk) * 256 + cc];
        }
        __syncthreads();
#pragma unroll
        for (int k = 0; k < 64; ++k) {
            float a0 = Hs[r][kt + k], a1 = Hs[r + 16][kt + k];
#pragma unroll
            for (int j = 0; j < 16; ++j) {
                float b = B1s[k][cb * 16 + j];
                acc[0][j] = fmaf(a0, b, acc[0][j]);
                acc[1][j] = fmaf(a1, b, acc[1][j]);
            }
        }
        __syncthreads();
    }
#pragma unroll
    for (int i = 0; i < 2; ++i)
#pragma unroll
        for (int j = 0; j < 16; ++j) {
            int col = cb * 16 + j;
            Ts[r + i * 16][col] = fmaxf(acc[i][j] + b1[col], 0.f);
        }

    // ---- phase B: out = h + T @ W2 + b2 ----
    float acc2[2][8];
#pragma unroll
    for (int i = 0; i < 2; ++i)
#pragma unroll
        for (int j = 0; j < 8; ++j) acc2[i][j] = 0.f;

    for (int kt = 0; kt < 256; kt += 64) {
        for (int u = tid; u < 2048; u += 256) {       // B2s 64x128
            int kk = u >> 5, cc = (u & 31) * 4;
            *(float4*)&B2s[kk][cc] = *(const float4*)&W2[(kt + kk) * 128 + cc];
        }
        __syncthreads();                              // first one also publishes Ts
#pragma unroll
        for (int k = 0; k < 64; ++k) {
            float a0 = Ts[r][kt + k], a1 = Ts[r + 16][kt + k];
#pragma unroll
            for (int j = 0; j < 8; ++j) {
                float b = B2s[k][cb * 8 + j];
                acc2[0][j] = fmaf(a0, b, acc2[0][j]);
                acc2[1][j] = fmaf(a1, b, acc2[1][j]);
            }
        }
        __syncthreads();
    }
#pragma unroll
    for (int i = 0; i < 2; ++i) {
        int row = row0 + r + i * 16;
#pragma unroll
        for (int j = 0; j < 8; ++j) {
            int col = cb * 8 + j;
            out[row * 128 + col] = Hs[r + i * 16][col] + acc2[i][j] + b2[col];
        }
    }
}

extern "C" void kernel_launch(void* const* d_in, const int* in_sizes, int n_in,
                              void* d_out, int out_size, void* d_ws, size_t ws_size,
                              hipStream_t stream)
{
    const float* q  = (const float*)d_in[0];
    // d_in[1] = k : dead (per-node q·k dot is segment-constant, cancels in softmax)
    const float* v  = (const float*)d_in[2];
    const float* ef = (const float*)d_in[3];
    const float* H  = (const float*)d_in[4];
    // d_in[5] = Wq, d_in[6] = Wk : dead
    const float* Wv = (const float*)d_in[7];
    const float* We = (const float*)d_in[8];
    const float* be = (const float*)d_in[9];
    const float* Wo = (const float*)d_in[10];
    const float* W1 = (const float*)d_in[11];
    const float* b1 = (const float*)d_in[12];
    const float* W2 = (const float*)d_in[13];
    const float* b2 = (const float*)d_in[14];
    float* out = (float*)d_out;

    char* w = (char*)d_ws;
    auto carve = [&](size_t bytes) -> void* {
        void* p = (void*)w;
        w += (bytes + 255) & ~(size_t)255;
        return p;
    };
    int* edge_cnt   = (int*)carve(N_EDGES * 4);                    // 32 KB  (zeroed)
    int* node_cnt   = (int*)carve(N_NODES * 4);                    // 64 KB  (zeroed)
    size_t zero_bytes = (size_t)(w - (char*)d_ws);
    int* edge_nodes = (int*)carve((size_t)N_EDGES * MAXD * 4);     // 1 MB
    int* node_edges = (int*)carve((size_t)N_NODES * NODE_CAP * 4); // 4 MB
    float* pe       = (float*)carve((size_t)N_NODES * 8 * 4);
    float* eexp     = (float*)carve((size_t)N_EDGES * 8 * 4);
    float* s_arr    = (float*)carve((size_t)N_NODES * 8 * 4);
    float* vsrc     = (float*)carve((size_t)N_NODES * 128 * 4);    // 8 MB
    float* msg      = (float*)carve((size_t)N_EDGES * 128 * 4);    // 4 MB
    (void)ws_size; (void)in_sizes; (void)n_in; (void)out_size;

    hipMemsetAsync(d_ws, 0, zero_bytes, stream);

    phase1_k<<<5120, 256, 0, stream>>>(v, Wv, ef, We, H, edge_cnt, edge_nodes,
                                       node_cnt, node_edges, vsrc, pe);
    eexp_k<<<(N_EDGES * 8) / 256, 256, 0, stream>>>(edge_cnt, edge_nodes, pe, be, eexp);
    z_k<<<(N_NODES * 8) / 256, 256, 0, stream>>>(node_cnt, node_edges, eexp, s_arr);
    msg_k<<<(N_EDGES * 32) / 256, 256, 0, stream>>>(edge_cnt, edge_nodes, eexp,
                                                    s_arr, vsrc, msg);
    ffn_agg_k<<<N_NODES / 32, 256, 0, stream>>>(q, node_cnt, node_edges, msg, Wo,
                                                W1, b1, W2, b2, out);
}